// Round 1
// baseline (1653.902 us; speedup 1.0000x reference)
//
#include <hip/hip_runtime.h>

// ---------------- CSR build ----------------

__global__ void hist_kernel(const int* __restrict__ dst, int* __restrict__ deg, int E) {
    int i = blockIdx.x * blockDim.x + threadIdx.x;
    if (i < E) atomicAdd(&deg[dst[i]], 1);
}

__global__ void scan_kernel(const int* __restrict__ deg, int* __restrict__ ptr, int n) {
    __shared__ int sdata[1024];
    __shared__ int srun;
    int tid = threadIdx.x;
    if (tid == 0) srun = 0;
    __syncthreads();
    for (int base = 0; base < n; base += 1024) {
        int i = base + tid;
        int v = (i < n) ? deg[i] : 0;
        sdata[tid] = v;
        __syncthreads();
        for (int off = 1; off < 1024; off <<= 1) {
            int t = (tid >= off) ? sdata[tid - off] : 0;
            __syncthreads();
            sdata[tid] += t;
            __syncthreads();
        }
        int run = srun;
        if (i < n) ptr[i] = run + sdata[tid] - v;   // exclusive scan
        __syncthreads();
        if (tid == 1023) srun = run + sdata[1023];
        __syncthreads();
    }
    if (tid == 0) ptr[n] = srun;
}

__global__ void scatter_kernel(const int* __restrict__ src, const int* __restrict__ dst,
                               const float* __restrict__ e, int* __restrict__ cursor,
                               int* __restrict__ srcs, float* __restrict__ w, int E) {
    int i = blockIdx.x * blockDim.x + threadIdx.x;
    if (i >= E) return;
    int d = dst[i];
    int pos = atomicAdd(&cursor[d], 1);
    srcs[pos] = src[i];
    float4 ev = *reinterpret_cast<const float4*>(e + (size_t)i * 4);
    *reinterpret_cast<float4*>(w + (size_t)pos * 4) = ev;
}

// Fused e_sum + divide: per (node, head) thread normalizes its CSR range in place.
__global__ void normalize_kernel(const int* __restrict__ ptr, float* __restrict__ w, int N) {
    int t = blockIdx.x * blockDim.x + threadIdx.x;
    if (t >= N * 4) return;
    int node = t >> 2, k = t & 3;
    int b = ptr[node], e = ptr[node + 1];
    float s = 0.f;
    for (int p = b; p < e; ++p) s += w[p * 4 + k];
    if (b < e) {
        float inv = 1.0f / s;
        for (int p = b; p < e; ++p) w[p * 4 + k] *= inv;
    }
}

// ---------------- f(x) = A x - x  (CSR gather, no atomics) ----------------
// One block of 128 threads per node: thread t covers (head=t>>5, dh=t&31).
__global__ __launch_bounds__(128) void feval_kernel(
        const int* __restrict__ ptr, const int* __restrict__ srcs,
        const float* __restrict__ w, const float* __restrict__ x,
        float* __restrict__ out) {
    int node = blockIdx.x;
    int t = threadIdx.x;
    int k = t >> 5;
    int b = ptr[node], e = ptr[node + 1];
    float acc = 0.f;
    int p = b;
    for (; p + 1 < e; p += 2) {
        int s0 = srcs[p], s1 = srcs[p + 1];
        float w0 = w[p * 4 + k], w1 = w[(p + 1) * 4 + k];
        float x0 = x[(size_t)s0 * 128 + t];
        float x1 = x[(size_t)s1 * 128 + t];
        acc = fmaf(w0, x0, acc);
        acc = fmaf(w1, x1, acc);
    }
    if (p < e) {
        int s0 = srcs[p];
        acc = fmaf(w[p * 4 + k], x[(size_t)s0 * 128 + t], acc);
    }
    out[(size_t)node * 128 + t] = acc - x[(size_t)node * 128 + t];  // gamma = 1
}

// ---------------- RK stage combines: out = x + sum a[j]*k[j] ----------------
struct Terms { const float* k[5]; float a[5]; };

template <int NT>
__global__ __launch_bounds__(256) void comb_kernel(
        float* __restrict__ out, const float* __restrict__ xin, Terms tm, int n4) {
    int i = blockIdx.x * blockDim.x + threadIdx.x;
    if (i >= n4) return;
    float4 r = reinterpret_cast<const float4*>(xin)[i];
#pragma unroll
    for (int j = 0; j < NT; ++j) {
        float4 kv = reinterpret_cast<const float4*>(tm.k[j])[i];
        float a = tm.a[j];
        r.x = fmaf(a, kv.x, r.x);
        r.y = fmaf(a, kv.y, r.y);
        r.z = fmaf(a, kv.z, r.z);
        r.w = fmaf(a, kv.w, r.w);
    }
    reinterpret_cast<float4*>(out)[i] = r;
}

// ---------------- host ----------------

extern "C" void kernel_launch(void* const* d_in, const int* in_sizes, int n_in,
                              void* d_out, int out_size, void* d_ws, size_t ws_size,
                              hipStream_t stream) {
    const float* h   = (const float*)d_in[0];
    const float* e   = (const float*)d_in[1];
    const int*   src = (const int*)d_in[2];
    const int*   dst = (const int*)d_in[3];

    const int E = in_sizes[2];
    const int N = in_sizes[0] / 128;
    const int ND = N * 128;
    const int n4 = ND / 4;
    const int cblocks = (n4 + 255) / 256;

    char* ws = (char*)d_ws;
    size_t off = 0;
    auto alloc = [&](size_t b) { void* p = ws + off; off += (b + 255) & ~(size_t)255; return p; };
    int*   deg    = (int*)alloc((size_t)N * 4);
    int*   ptr    = (int*)alloc((size_t)(N + 1) * 4);
    int*   cursor = (int*)alloc((size_t)N * 4);
    int*   srcs   = (int*)alloc((size_t)E * 4);
    float* w      = (float*)alloc((size_t)E * 16);
    float* x      = (float*)alloc((size_t)ND * 4);
    float* xt     = (float*)alloc((size_t)ND * 4);
    float* kb[6];
    for (int i = 0; i < 6; ++i) kb[i] = (float*)alloc((size_t)ND * 4);

    // ---- setup: CSR by dst + normalized weights ----
    hipMemsetAsync(deg, 0, (size_t)N * 4, stream);
    hist_kernel<<<(E + 255) / 256, 256, 0, stream>>>(dst, deg, E);
    scan_kernel<<<1, 1024, 0, stream>>>(deg, ptr, N);
    hipMemcpyAsync(cursor, ptr, (size_t)N * 4, hipMemcpyDeviceToDevice, stream);
    scatter_kernel<<<(E + 255) / 256, 256, 0, stream>>>(src, dst, e, cursor, srcs, w, E);
    normalize_kernel<<<(N * 4 + 255) / 256, 256, 0, stream>>>(ptr, w, N);
    hipMemcpyAsync(x, h, (size_t)ND * 4, hipMemcpyDeviceToDevice, stream);

    const float dt = 1.0f / 8.0f;

    auto comb = [&](float* out, const float* xin, int nt, const float* const* ks, const float* as) {
        Terms tm{};
        for (int i = 0; i < nt; ++i) { tm.k[i] = ks[i]; tm.a[i] = as[i]; }
        switch (nt) {
            case 1: comb_kernel<1><<<cblocks, 256, 0, stream>>>(out, xin, tm, n4); break;
            case 2: comb_kernel<2><<<cblocks, 256, 0, stream>>>(out, xin, tm, n4); break;
            case 3: comb_kernel<3><<<cblocks, 256, 0, stream>>>(out, xin, tm, n4); break;
            case 4: comb_kernel<4><<<cblocks, 256, 0, stream>>>(out, xin, tm, n4); break;
            case 5: comb_kernel<5><<<cblocks, 256, 0, stream>>>(out, xin, tm, n4); break;
        }
    };

    for (int s = 0; s < 8; ++s) {
        // k1 = f(x)
        feval_kernel<<<N, 128, 0, stream>>>(ptr, srcs, w, x, kb[0]);
        { const float* ks[] = {kb[0]};
          float as[] = {dt * 0.2f};
          comb(xt, x, 1, ks, as); }
        // k2
        feval_kernel<<<N, 128, 0, stream>>>(ptr, srcs, w, xt, kb[1]);
        { const float* ks[] = {kb[0], kb[1]};
          float as[] = {dt * (3.0f / 40.0f), dt * (9.0f / 40.0f)};
          comb(xt, x, 2, ks, as); }
        // k3
        feval_kernel<<<N, 128, 0, stream>>>(ptr, srcs, w, xt, kb[2]);
        { const float* ks[] = {kb[0], kb[1], kb[2]};
          float as[] = {dt * (44.0f / 45.0f), dt * (-56.0f / 15.0f), dt * (32.0f / 9.0f)};
          comb(xt, x, 3, ks, as); }
        // k4
        feval_kernel<<<N, 128, 0, stream>>>(ptr, srcs, w, xt, kb[3]);
        { const float* ks[] = {kb[0], kb[1], kb[2], kb[3]};
          float as[] = {dt * (19372.0f / 6561.0f), dt * (-25360.0f / 2187.0f),
                        dt * (64448.0f / 6561.0f), dt * (-212.0f / 729.0f)};
          comb(xt, x, 4, ks, as); }
        // k5
        feval_kernel<<<N, 128, 0, stream>>>(ptr, srcs, w, xt, kb[4]);
        { const float* ks[] = {kb[0], kb[1], kb[2], kb[3], kb[4]};
          float as[] = {dt * (9017.0f / 3168.0f), dt * (-355.0f / 33.0f),
                        dt * (46732.0f / 5247.0f), dt * (49.0f / 176.0f),
                        dt * (-5103.0f / 18656.0f)};
          comb(xt, x, 5, ks, as); }
        // k6
        feval_kernel<<<N, 128, 0, stream>>>(ptr, srcs, w, xt, kb[5]);
        // x_new = x + dt*(35/384 k1 + 500/1113 k3 + 125/192 k4 - 2187/6784 k5 + 11/84 k6)
        { const float* ks[] = {kb[0], kb[2], kb[3], kb[4], kb[5]};
          float as[] = {dt * (35.0f / 384.0f), dt * (500.0f / 1113.0f),
                        dt * (125.0f / 192.0f), dt * (-2187.0f / 6784.0f),
                        dt * (11.0f / 84.0f)};
          float* out = (s == 7) ? (float*)d_out : x;
          comb(out, x, 5, ks, as); }
    }
}

// Round 2
// 1060.599 us; speedup vs baseline: 1.5594x; 1.5594x over previous
//
#include <hip/hip_runtime.h>

// ---------------- CSR build ----------------

__global__ void hist_kernel(const int* __restrict__ dst, int* __restrict__ deg, int E) {
    int i = blockIdx.x * blockDim.x + threadIdx.x;
    if (i < E) atomicAdd(&deg[dst[i]], 1);
}

__global__ void scan_kernel(const int* __restrict__ deg, int* __restrict__ ptr, int n) {
    __shared__ int sdata[1024];
    __shared__ int srun;
    int tid = threadIdx.x;
    if (tid == 0) srun = 0;
    __syncthreads();
    for (int base = 0; base < n; base += 1024) {
        int i = base + tid;
        int v = (i < n) ? deg[i] : 0;
        sdata[tid] = v;
        __syncthreads();
        for (int off = 1; off < 1024; off <<= 1) {
            int t = (tid >= off) ? sdata[tid - off] : 0;
            __syncthreads();
            sdata[tid] += t;
            __syncthreads();
        }
        int run = srun;
        if (i < n) ptr[i] = run + sdata[tid] - v;   // exclusive scan
        __syncthreads();
        if (tid == 1023) srun = run + sdata[1023];
        __syncthreads();
    }
    if (tid == 0) ptr[n] = srun;
}

__global__ void scatter_kernel(const int* __restrict__ src, const int* __restrict__ dst,
                               const float* __restrict__ e, int* __restrict__ cursor,
                               int* __restrict__ srcs, float* __restrict__ w, int E) {
    int i = blockIdx.x * blockDim.x + threadIdx.x;
    if (i >= E) return;
    int d = dst[i];
    int pos = atomicAdd(&cursor[d], 1);
    srcs[pos] = src[i];
    float4 ev = *reinterpret_cast<const float4*>(e + (size_t)i * 4);
    *reinterpret_cast<float4*>(w + (size_t)pos * 4) = ev;
}

// Fused e_sum + divide: per (node, head) thread normalizes its CSR range in place.
__global__ void normalize_kernel(const int* __restrict__ ptr, float* __restrict__ w, int N) {
    int t = blockIdx.x * blockDim.x + threadIdx.x;
    if (t >= N * 4) return;
    int node = t >> 2, k = t & 3;
    int b = ptr[node], e = ptr[node + 1];
    float s = 0.f;
    for (int p = b; p < e; ++p) s += w[p * 4 + k];
    if (b < e) {
        float inv = 1.0f / s;
        for (int p = b; p < e; ++p) w[p * 4 + k] *= inv;
    }
}

// ---------------- Horner stage: out = g*(A*yin - yin) + c*x ----------------
// DOPRI5 on a linear ODE == stability polynomial R(z)=sum a_k z^k, a_k=1/k! (k<=5), a6=1/600.
// One block of 128 threads per node: thread t covers (head=t>>5, dh=t&31).
__global__ __launch_bounds__(128) void matvec_kernel(
        const int* __restrict__ ptr, const int* __restrict__ srcs,
        const float* __restrict__ w, const float* __restrict__ yin,
        const float* __restrict__ x, float* __restrict__ out,
        float g, float c) {
    int node = blockIdx.x;
    int t = threadIdx.x;
    int k = t >> 5;
    int b = ptr[node], e = ptr[node + 1];
    float acc0 = 0.f, acc1 = 0.f;
    int p = b;
    for (; p + 3 < e; p += 4) {
        int s0 = srcs[p], s1 = srcs[p + 1], s2 = srcs[p + 2], s3 = srcs[p + 3];
        float w0 = w[p * 4 + k], w1 = w[(p + 1) * 4 + k];
        float w2 = w[(p + 2) * 4 + k], w3 = w[(p + 3) * 4 + k];
        float x0 = yin[(size_t)s0 * 128 + t];
        float x1 = yin[(size_t)s1 * 128 + t];
        float x2 = yin[(size_t)s2 * 128 + t];
        float x3 = yin[(size_t)s3 * 128 + t];
        acc0 = fmaf(w0, x0, acc0);
        acc1 = fmaf(w1, x1, acc1);
        acc0 = fmaf(w2, x2, acc0);
        acc1 = fmaf(w3, x3, acc1);
    }
    for (; p < e; ++p) {
        acc0 = fmaf(w[p * 4 + k], yin[(size_t)srcs[p] * 128 + t], acc0);
    }
    size_t o = (size_t)node * 128 + t;
    out[o] = fmaf(g, (acc0 + acc1) - yin[o], c * x[o]);
}

// ---------------- host ----------------

extern "C" void kernel_launch(void* const* d_in, const int* in_sizes, int n_in,
                              void* d_out, int out_size, void* d_ws, size_t ws_size,
                              hipStream_t stream) {
    const float* h   = (const float*)d_in[0];
    const float* e   = (const float*)d_in[1];
    const int*   src = (const int*)d_in[2];
    const int*   dst = (const int*)d_in[3];

    const int E = in_sizes[2];
    const int N = in_sizes[0] / 128;
    const int ND = N * 128;

    char* ws = (char*)d_ws;
    size_t off = 0;
    auto alloc = [&](size_t b) { void* p = ws + off; off += (b + 255) & ~(size_t)255; return p; };
    int*   deg    = (int*)alloc((size_t)N * 4);
    int*   ptr    = (int*)alloc((size_t)(N + 1) * 4);
    int*   cursor = (int*)alloc((size_t)N * 4);
    int*   srcs   = (int*)alloc((size_t)E * 4);
    float* w      = (float*)alloc((size_t)E * 16);
    float* x      = (float*)alloc((size_t)ND * 4);
    float* y0     = (float*)alloc((size_t)ND * 4);
    float* y1     = (float*)alloc((size_t)ND * 4);

    // ---- setup: CSR by dst + normalized weights ----
    hipMemsetAsync(deg, 0, (size_t)N * 4, stream);
    hist_kernel<<<(E + 255) / 256, 256, 0, stream>>>(dst, deg, E);
    scan_kernel<<<1, 1024, 0, stream>>>(deg, ptr, N);
    hipMemcpyAsync(cursor, ptr, (size_t)N * 4, hipMemcpyDeviceToDevice, stream);
    scatter_kernel<<<(E + 255) / 256, 256, 0, stream>>>(src, dst, e, cursor, srcs, w, E);
    normalize_kernel<<<(N * 4 + 255) / 256, 256, 0, stream>>>(ptr, w, N);
    hipMemcpyAsync(x, h, (size_t)ND * 4, hipMemcpyDeviceToDevice, stream);

    const float dt = 1.0f / 8.0f;
    // R(z) = 1 + z + z^2/2 + z^3/6 + z^4/24 + z^5/120 + z^6/600
    const float a2 = 0.5f, a3 = 1.0f / 6.0f, a4 = 1.0f / 24.0f,
                a5 = 1.0f / 120.0f, a6 = 1.0f / 600.0f;

    for (int s = 0; s < 8; ++s) {
        // Horner: y = M*(a6*x) + a5*x ; then y = M*y + a_k*x ... (M = dt*(A - I))
        matvec_kernel<<<N, 128, 0, stream>>>(ptr, srcs, w, x,  x, y0, dt * a6, a5);
        matvec_kernel<<<N, 128, 0, stream>>>(ptr, srcs, w, y0, x, y1, dt,      a4);
        matvec_kernel<<<N, 128, 0, stream>>>(ptr, srcs, w, y1, x, y0, dt,      a3);
        matvec_kernel<<<N, 128, 0, stream>>>(ptr, srcs, w, y0, x, y1, dt,      a2);
        matvec_kernel<<<N, 128, 0, stream>>>(ptr, srcs, w, y1, x, y0, dt,      1.0f);
        float* out = (s == 7) ? (float*)d_out : x;
        matvec_kernel<<<N, 128, 0, stream>>>(ptr, srcs, w, y0, x, out, dt,     1.0f);
    }
}